// Round 11
// baseline (200.073 us; speedup 1.0000x reference)
//
#include <hip/hip_runtime.h>
#include <cmath>

#define NWALK 4096
#define NXD   48
#define HID   256
#define WPB   8
#define GCONST 0.7978845608028654f

typedef _Float16 half8   __attribute__((ext_vector_type(8)));
typedef float    float4v __attribute__((ext_vector_type(4)));

// ---------- prep_all: blocks 0..15: W2 transpose->fp16 + W1 cast; blocks 16..271: layer-1
__global__ __launch_bounds__(256) void prep_all(const float* __restrict__ W2,
                                                const float* __restrict__ W1,
                                                const float* __restrict__ x,
                                                const float* __restrict__ b1,
                                                _Float16* __restrict__ W2c,
                                                _Float16* __restrict__ W1c,
                                                _Float16* __restrict__ t1h,
                                                _Float16* __restrict__ h1h,
                                                _Float16* __restrict__ ch) {
    __shared__ float tile[64][65];
    __shared__ float xs[16][NXD];

    if (blockIdx.x < 16) {
        const int bi = blockIdx.x & 3;
        const int bj = blockIdx.x >> 2;
        const int tx = threadIdx.x & 63;
        const int ty = threadIdx.x >> 6;
        #pragma unroll
        for (int r = 0; r < 16; ++r) {
            int il = ty * 16 + r;
            tile[tx][il] = W2[(bi * 64 + il) * HID + bj * 64 + tx];
        }
        __syncthreads();
        #pragma unroll
        for (int r = 0; r < 16; ++r) {
            int jl = ty * 16 + r;
            W2c[(bj * 64 + jl) * HID + bi * 64 + tx] = (_Float16)tile[jl][tx];
        }
        #pragma unroll
        for (int r = 0; r < 3; ++r) {
            int k = blockIdx.x * 3 + r;
            W1c[k * HID + threadIdx.x] = (_Float16)W1[k * HID + threadIdx.x];
        }
    } else {
        const int i  = threadIdx.x;
        const int w0 = (blockIdx.x - 16) * 16;

        float col[NXD];
        float S = 0.f;
        #pragma unroll
        for (int k = 0; k < NXD; ++k) {
            float v = W1[k * HID + i];
            col[k] = v;
            S = fmaf(v, v, S);
        }
        #pragma unroll
        for (int t = threadIdx.x; t < 16 * NXD; t += 256)
            ((float*)xs)[t] = x[w0 * NXD + t];
        __syncthreads();

        const float b = b1[i];
        #pragma unroll 4
        for (int w = 0; w < 16; ++w) {
            float a1 = b;
            #pragma unroll
            for (int k = 0; k < NXD; ++k)
                a1 = fmaf(xs[w][k], col[k], a1);
            float h1 = tanhf(a1);
            float t1 = 1.f - h1 * h1;
            int off = (w0 + w) * HID + i;
            t1h[off] = (_Float16)t1;
            h1h[off] = (_Float16)h1;
            ch[off]  = (_Float16)(S * h1 * t1);
        }
    }
}

// ---------- eloc8: 512 threads (8 waves), 2 j-tiles/wave, A-residency 64 regs, lean diet
__global__ __launch_bounds__(512, 4) void eloc8(
    const float* __restrict__ x,
    const float* __restrict__ b2,
    const float* __restrict__ w3,
    const _Float16* __restrict__ W2c,
    const _Float16* __restrict__ W1c,
    const _Float16* __restrict__ t1h,
    const _Float16* __restrict__ h1h,
    const _Float16* __restrict__ ch,
    float* __restrict__ out)
{
    __shared__ __align__(16) _Float16 AsT[2][50 * HID];   // 51.2 KB, walker-parity
    __shared__ float xs[WPB][NXD];
    __shared__ float b2s[HID], w3s[HID];
    __shared__ float a2s[HID], ps[HID], us[HID], uh2s[HID];  // wave-local use
    __shared__ float gw[2][8][NXD];                       // parity-buffered
    __shared__ float wred[2][8][2];                       // parity-buffered

    const int w0   = blockIdx.x * WPB;
    const int tid  = threadIdx.x;          // 0..511
    const int wave = tid >> 6;             // 0..7
    const int lane = tid & 63;
    const int n16  = lane & 15;
    const int quad = lane >> 4;
    const int ci   = tid & 31;             // staging i-chunk (8 halfs)
    const int kr0  = (tid >> 5) & 15;      // staging k-row base 0..15

    // ---- full A-residency: 8 steps x 2 j-tiles = 64 VGPRs (the ONLY big resident) ----
    half8 afr[8][2];
    #pragma unroll
    for (int s = 0; s < 8; ++s)
        #pragma unroll
        for (int a = 0; a < 2; ++a)
            afr[s][a] = *(const half8*)(W2c + ((wave * 2 + a) * 16 + n16) * HID
                                        + s * 32 + quad * 8);

    // block-constant staging
    if (tid < HID) { b2s[tid] = b2[tid]; w3s[tid] = w3[tid]; }
    if (tid < WPB * NXD) ((float*)xs)[tid] = x[w0 * NXD + tid];

    // stage walker 0 into buffer 0 (W1c streamed from L2, not resident)
    {
        half8 th = *(const half8*)(t1h + w0 * HID + ci * 8);
        #pragma unroll
        for (int s2 = 0; s2 < 3; ++s2) {
            int k = s2 * 16 + kr0;
            half8 wv = *(const half8*)(W1c + k * HID + ci * 8);
            *(half8*)(AsT[0] + k * HID + ((ci ^ (k & 7)) * 8)) = wv * th;
        }
        if (tid < 32) {
            half8 hv = *(const half8*)(h1h + w0 * HID + tid * 8);
            *(half8*)(AsT[0] + 48 * HID + tid * 8) = hv;                  // 48&7=0
        } else if (tid < 64) {
            int c2 = tid - 32;
            half8 cv = *(const half8*)(ch + w0 * HID + c2 * 8);
            *(half8*)(AsT[0] + 49 * HID + ((c2 ^ 1) * 8)) = cv;           // 49&7=1
        }
    }
    __syncthreads();

    for (int ww = 0; ww < WPB; ++ww) {
        const int cur = ww & 1, nxt = cur ^ 1;
        const int wg  = w0 + ww;
        const _Float16* curA = AsT[cur];
        const bool more = (ww + 1 < WPB);

        // ---- pass kt=3 first: a2 (col 0) / p (col 1) ----
        float4v acc3[2];
        acc3[0] = (float4v){0.f, 0.f, 0.f, 0.f};
        acc3[1] = (float4v){0.f, 0.f, 0.f, 0.f};
        {
            const int krow = 48 + (n16 & 1);
            #pragma unroll
            for (int s = 0; s < 8; ++s) {
                half8 bf = *(const half8*)(curA + krow * HID
                            + ((((s * 4 + quad) ^ (krow & 7)) << 3)));
                acc3[0] = __builtin_amdgcn_mfma_f32_16x16x32_f16(afr[s][0], bf, acc3[0], 0, 0, 0);
                acc3[1] = __builtin_amdgcn_mfma_f32_16x16x32_f16(afr[s][1], bf, acc3[1], 0, 0, 0);
            }
        }

        // ---- early staging GLOBAL loads (vmcnt; do not block the LDS chain) ----
        half8 th, hcv, wv0, wv1, wv2;
        if (more) {
            const int wn = wg + 1;
            th  = *(const half8*)(t1h + wn * HID + ci * 8);
            wv0 = *(const half8*)(W1c + (0 * 16 + kr0) * HID + ci * 8);
            wv1 = *(const half8*)(W1c + (1 * 16 + kr0) * HID + ci * 8);
            wv2 = *(const half8*)(W1c + (2 * 16 + kr0) * HID + ci * 8);
            if (tid < 32)      hcv = *(const half8*)(h1h + wn * HID + tid * 8);
            else if (tid < 64) hcv = *(const half8*)(ch + wn * HID + (tid - 32) * 8);
        }

        // ---- a2/p scatter (wave-local) ----
        if (n16 == 0) {
            #pragma unroll
            for (int a = 0; a < 2; ++a)
                #pragma unroll
                for (int reg = 0; reg < 4; ++reg)
                    a2s[(wave * 2 + a) * 16 + quad * 4 + reg] = acc3[a][reg];
        } else if (n16 == 1) {
            #pragma unroll
            for (int a = 0; a < 2; ++a)
                #pragma unroll
                for (int reg = 0; reg < 4; ++reg)
                    ps[(wave * 2 + a) * 16 + quad * 4 + reg] = acc3[a][reg];
        }

        // ---- distributed activation: lanes 0..31 handle the wave's 32 j values ----
        float rt2 = 0.f;
        if (lane < 32) {
            int j2 = wave * 32 + lane;
            float a2v = a2s[j2] + b2s[j2];
            float h2  = tanhf(a2v);
            float t2  = 1.f - h2 * h2;
            float u   = w3s[j2] * t2;
            us[j2]    = u;
            uh2s[j2]  = u * h2;
            rt2 = u * ps[j2];
        }

        // ---- uu preload only (8 regs); uh read per-pass from LDS ----
        float4v uu_r[2];
        #pragma unroll
        for (int a = 0; a < 2; ++a)
            uu_r[a] = *(const float4v*)(us + (wave * 2 + a) * 16 + quad * 4);

        // ---- staging LDS writes for next walker ----
        if (more) {
            *(half8*)(AsT[nxt] + (0 * 16 + kr0) * HID + ((ci ^ (kr0 & 7)) * 8)) = wv0 * th;
            {
                int k1 = 16 + kr0;
                *(half8*)(AsT[nxt] + k1 * HID + ((ci ^ (k1 & 7)) * 8)) = wv1 * th;
            }
            {
                int k2 = 32 + kr0;
                *(half8*)(AsT[nxt] + k2 * HID + ((ci ^ (k2 & 7)) * 8)) = wv2 * th;
            }
            if (tid < 32)      *(half8*)(AsT[nxt] + 48 * HID + tid * 8) = hcv;
            else if (tid < 64) *(half8*)(AsT[nxt] + 49 * HID + (((tid - 32) ^ 1) * 8)) = hcv;
        }

        // ---- kt = 0..2 passes, 8-reg accumulator reused, immediate fold ----
        float rt1 = 0.f;
        float gp[3];
        #pragma unroll 1
        for (int kt = 0; kt < 3; ++kt) {
            float4v acc[2];
            acc[0] = (float4v){0.f, 0.f, 0.f, 0.f};
            acc[1] = (float4v){0.f, 0.f, 0.f, 0.f};
            const int krow = kt * 16 + n16;
            #pragma unroll
            for (int s = 0; s < 8; ++s) {
                half8 bf = *(const half8*)(curA + krow * HID
                            + ((((s * 4 + quad) ^ (krow & 7)) << 3)));
                acc[0] = __builtin_amdgcn_mfma_f32_16x16x32_f16(afr[s][0], bf, acc[0], 0, 0, 0);
                acc[1] = __builtin_amdgcn_mfma_f32_16x16x32_f16(afr[s][1], bf, acc[1], 0, 0, 0);
            }
            float g = 0.f;
            #pragma unroll
            for (int a = 0; a < 2; ++a) {
                float4v uhv = *(const float4v*)(uh2s + (wave * 2 + a) * 16 + quad * 4);
                #pragma unroll
                for (int reg = 0; reg < 4; ++reg) {
                    float m = acc[a][reg];
                    rt1 = fmaf(m * m, uhv[reg], rt1);
                    g   = fmaf(m, uu_r[a][reg], g);
                }
            }
            gp[kt] = g;
        }

        // ---- reductions ----
        #pragma unroll
        for (int off = 32; off > 0; off >>= 1) {
            rt1 += __shfl_down(rt1, off, 64);
            rt2 += __shfl_down(rt2, off, 64);
        }
        #pragma unroll
        for (int kt = 0; kt < 3; ++kt) {
            gp[kt] += __shfl_xor(gp[kt], 16, 64);
            gp[kt] += __shfl_xor(gp[kt], 32, 64);
        }
        if (lane == 0) { wred[cur][wave][0] = rt1; wred[cur][wave][1] = rt2; }
        if (lane < 16) {
            #pragma unroll
            for (int kt = 0; kt < 3; ++kt) gw[cur][wave][kt * 16 + lane] = gp[kt];
        }

        __syncthreads();   // AsT[nxt] ready; gw/wred[cur] ready

        // ---- final combine for walker ww (wave 0; parity protects) ----
        if (wave == 0) {
            float ggp = 0.f, potp = 0.f;
            if (lane < NXD) {
                float g = 0.f;
                #pragma unroll
                for (int v = 0; v < 8; ++v) g += gw[cur][v][lane];
                ggp = g * g;
                float xq = xs[ww][lane];
                potp = 0.5f * xq * xq;
            }
            #pragma unroll
            for (int off = 32; off > 0; off >>= 1) {
                ggp  += __shfl_down(ggp, off, 64);
                potp += __shfl_down(potp, off, 64);
            }
            if (lane == 0) {
                float T1 = 0.f, T2 = 0.f;
                #pragma unroll
                for (int v = 0; v < 8; ++v) { T1 += wred[cur][v][0]; T2 += wred[cur][v][1]; }
                float kin = T1 + T2 - 0.5f * ggp;

                float x0 = xs[ww][0], x1 = xs[ww][1], x2 = xs[ww][2];
                float x3 = xs[ww][3], x4 = xs[ww][4], x5 = xs[ww][5];
                float d01 = (x0-x1)*(x0-x1) + (x2-x1)*(x2-x1);
                float d02 = (x0-x2)*(x0-x2) + (x1-x2)*(x1-x2);
                float d12 = (x3-x5)*(x3-x5) + (x4-x5)*(x4-x5);
                float inter = GCONST * (expf(-2.f*d01) + expf(-2.f*d02) + expf(-2.f*d12));

                out[wg]             = kin + potp + inter;
                out[NWALK + wg]     = kin;
                out[2 * NWALK + wg] = potp;
                out[3 * NWALK + wg] = inter;
            }
        }
    }
}

extern "C" void kernel_launch(void* const* d_in, const int* in_sizes, int n_in,
                              void* d_out, int out_size, void* d_ws, size_t ws_size,
                              hipStream_t stream) {
    const float* x  = (const float*)d_in[0];
    const float* W1 = (const float*)d_in[1];
    const float* b1 = (const float*)d_in[2];
    const float* W2 = (const float*)d_in[3];
    const float* b2 = (const float*)d_in[4];
    const float* w3 = (const float*)d_in[5];
    float* out = (float*)d_out;

    char* ws = (char*)d_ws;
    _Float16* W2c = (_Float16*)(ws);                       // 128 KB
    _Float16* W1c = (_Float16*)(ws + 131072);              // 24 KB
    _Float16* t1h = (_Float16*)(ws + 155648);              // 2 MB
    _Float16* h1h = (_Float16*)(ws + 2252800);             // 2 MB
    _Float16* chv = (_Float16*)(ws + 4349952);             // 2 MB

    prep_all<<<16 + NWALK / 16, 256, 0, stream>>>(W2, W1, x, b1, W2c, W1c, t1h, h1h, chv);
    eloc8<<<NWALK / WPB, 512, 0, stream>>>(x, b2, w3, W2c, W1c, t1h, h1h, chv, out);
}

// Round 12
// 175.789 us; speedup vs baseline: 1.1381x; 1.1381x over previous
//
#include <hip/hip_runtime.h>
#include <cmath>

#define NWALK 4096
#define NXD   48
#define HID   256
#define WPB   8
#define GCONST 0.7978845608028654f

typedef _Float16 half8   __attribute__((ext_vector_type(8)));
typedef float    float4v __attribute__((ext_vector_type(4)));

// ---------- prep_w: W2c[j*256+i] = fp16(W2[i*256+j]) (tiled transpose) + W1 fp16 cast
__global__ __launch_bounds__(256) void prep_w(const float* __restrict__ W2,
                                              const float* __restrict__ W1,
                                              _Float16* __restrict__ W2c,
                                              _Float16* __restrict__ W1c) {
    __shared__ float tile[64][65];
    const int bi = blockIdx.x & 3;
    const int bj = blockIdx.x >> 2;
    const int tx = threadIdx.x & 63;
    const int ty = threadIdx.x >> 6;
    #pragma unroll
    for (int r = 0; r < 16; ++r) {
        int il = ty * 16 + r;
        tile[tx][il] = W2[(bi * 64 + il) * HID + bj * 64 + tx];
    }
    __syncthreads();
    #pragma unroll
    for (int r = 0; r < 16; ++r) {
        int jl = ty * 16 + r;
        W2c[(bj * 64 + jl) * HID + bi * 64 + tx] = (_Float16)tile[jl][tx];
    }
    #pragma unroll
    for (int r = 0; r < 3; ++r) {
        int k = blockIdx.x * 3 + r;
        W1c[k * HID + threadIdx.x] = (_Float16)W1[k * HID + threadIdx.x];
    }
}

// ---------- eloc8: 256 thr, full A-residency (128 regs), kt-split, in-block layer-1
__global__ __launch_bounds__(256, 2) void eloc8(
    const float* __restrict__ x,
    const float* __restrict__ W1,
    const float* __restrict__ b1,
    const float* __restrict__ b2,
    const float* __restrict__ w3,
    const _Float16* __restrict__ W2c,
    const _Float16* __restrict__ W1c,
    float* __restrict__ out)
{
    __shared__ __align__(16) _Float16 AsT[2][50 * HID];   // 51.2 KB, walker-parity
    __shared__ __align__(16) _Float16 t1L[WPB][HID];      // 4 KB
    __shared__ __align__(16) _Float16 h1L[WPB][HID];      // 4 KB
    __shared__ __align__(16) _Float16 cL[WPB][HID];       // 4 KB
    __shared__ float xs[WPB][NXD];
    __shared__ float b2s[HID], w3s[HID];
    __shared__ float a2s[HID], ps[HID], us[HID], uh2s[HID];
    __shared__ float gw[2][4][NXD];                       // parity-buffered
    __shared__ float wred[2][4][2];                       // parity-buffered

    const int w0   = blockIdx.x * WPB;
    const int tid  = threadIdx.x;
    const int wave = tid >> 6;
    const int lane = tid & 63;
    const int n16  = lane & 15;
    const int quad = (tid >> 4) & 3;
    const int ci   = tid & 31;     // staging i-chunk
    const int k0   = tid >> 5;     // staging k-row base

    // ---- FULL A-residency: 8 steps x 4 j-tiles = 128 regs, loaded ONCE ----
    half8 afr[8][4];
    #pragma unroll
    for (int s = 0; s < 8; ++s)
        #pragma unroll
        for (int a = 0; a < 4; ++a)
            afr[s][a] = *(const half8*)(W2c + ((wave * 4 + a) * 16 + n16) * HID
                                        + s * 32 + quad * 8);

    // block-constant staging
    b2s[tid] = b2[tid];
    w3s[tid] = w3[tid];
    #pragma unroll
    for (int t = tid; t < WPB * NXD; t += 256)
        ((float*)xs)[t] = x[w0 * NXD + t];
    __syncthreads();   // xs ready

    // ---- in-block layer 1: thread = hidden unit i, all 8 walkers ----
    {
        const int i = tid;
        float a1[WPB];
        #pragma unroll
        for (int w = 0; w < WPB; ++w) a1[w] = b1[i];
        float S = 0.f;
        #pragma unroll
        for (int k = 0; k < NXD; ++k) {
            float v = W1[k * HID + i];              // coalesced
            S = fmaf(v, v, S);
            #pragma unroll
            for (int w = 0; w < WPB; ++w)
                a1[w] = fmaf(xs[w][k], v, a1[w]);
        }
        #pragma unroll
        for (int w = 0; w < WPB; ++w) {
            float h1 = tanhf(a1[w]);
            float t1 = 1.f - h1 * h1;
            t1L[w][i] = (_Float16)t1;
            h1L[w][i] = (_Float16)h1;
            cL[w][i]  = (_Float16)(S * h1 * t1);
        }
    }
    __syncthreads();   // t1L/h1L/cL ready

    // stage walker 0 into buffer 0
    {
        half8 th = *(const half8*)(&t1L[0][ci * 8]);
        #pragma unroll
        for (int s2 = 0; s2 < 6; ++s2) {
            int k = s2 * 8 + k0;
            half8 wv = *(const half8*)(W1c + k * HID + ci * 8);
            *(half8*)(AsT[0] + k * HID + ((ci ^ (k & 7)) * 8)) = wv * th;
        }
        if (tid < 32) {
            half8 hv = *(const half8*)(&h1L[0][tid * 8]);
            *(half8*)(AsT[0] + 48 * HID + tid * 8) = hv;                  // 48&7=0
        } else if (tid < 64) {
            int c2 = tid - 32;
            half8 cv = *(const half8*)(&cL[0][c2 * 8]);
            *(half8*)(AsT[0] + 49 * HID + ((c2 ^ 1) * 8)) = cv;           // 49&7=1
        }
    }
    __syncthreads();

    for (int ww = 0; ww < WPB; ++ww) {
        const int cur = ww & 1, nxt = cur ^ 1;
        const int wg  = w0 + ww;
        const _Float16* curA = AsT[cur];
        const bool more = (ww + 1 < WPB);

        // ---- pass kt=3 first: a2 (col 0) / p (col 1) ----
        {
            float4v acc[4];
            #pragma unroll
            for (int a = 0; a < 4; ++a) acc[a] = (float4v){0.f, 0.f, 0.f, 0.f};
            const int krow = 48 + (n16 & 1);
            #pragma unroll
            for (int s = 0; s < 8; ++s) {
                half8 bf = *(const half8*)(curA + krow * HID
                            + ((((s * 4 + quad) ^ (krow & 7)) << 3)));
                #pragma unroll
                for (int a = 0; a < 4; ++a)
                    acc[a] = __builtin_amdgcn_mfma_f32_16x16x32_f16(
                        afr[s][a], bf, acc[a], 0, 0, 0);
            }
            if (n16 == 0) {
                #pragma unroll
                for (int a = 0; a < 4; ++a)
                    #pragma unroll
                    for (int reg = 0; reg < 4; ++reg)
                        a2s[(wave * 4 + a) * 16 + quad * 4 + reg] = acc[a][reg];
            } else if (n16 == 1) {
                #pragma unroll
                for (int a = 0; a < 4; ++a)
                    #pragma unroll
                    for (int reg = 0; reg < 4; ++reg)
                        ps[(wave * 4 + a) * 16 + quad * 4 + reg] = acc[a][reg];
            }
        }

        // ---- distributed activation: 1 tanh per thread (wave-local LDS) ----
        float a2v = a2s[tid] + b2s[tid];
        float h2  = tanhf(a2v);
        float t2  = 1.f - h2 * h2;
        float u   = w3s[tid] * t2;
        us[tid]   = u;
        uh2s[tid] = u * h2;
        float rt2 = u * ps[tid];

        // vectorized uu/uh preload (8 x ds_read_b128, 32 regs)
        float4v uu_r[4], uh_r[4];
        #pragma unroll
        for (int a = 0; a < 4; ++a) {
            int j0 = (wave * 4 + a) * 16 + quad * 4;
            uu_r[a] = *(const float4v*)(us + j0);
            uh_r[a] = *(const float4v*)(uh2s + j0);
        }

        // ---- kt = 0..2 passes, 16-reg accumulator reused, immediate fold ----
        float rt1 = 0.f;
        float gp[3];
        #pragma unroll 1
        for (int kt = 0; kt < 3; ++kt) {
            float4v acc[4];
            #pragma unroll
            for (int a = 0; a < 4; ++a) acc[a] = (float4v){0.f, 0.f, 0.f, 0.f};
            const int krow = kt * 16 + n16;
            #pragma unroll
            for (int s = 0; s < 8; ++s) {
                half8 bf = *(const half8*)(curA + krow * HID
                            + ((((s * 4 + quad) ^ (krow & 7)) << 3)));
                #pragma unroll
                for (int a = 0; a < 4; ++a)
                    acc[a] = __builtin_amdgcn_mfma_f32_16x16x32_f16(
                        afr[s][a], bf, acc[a], 0, 0, 0);
            }
            float g = 0.f;
            #pragma unroll
            for (int a = 0; a < 4; ++a)
                #pragma unroll
                for (int reg = 0; reg < 4; ++reg) {
                    float m = acc[a][reg];
                    rt1 = fmaf(m * m, uh_r[a][reg], rt1);
                    g   = fmaf(m, uu_r[a][reg], g);
                }
            gp[kt] = g;
        }

        // ---- stage next walker into other buffer (sources in LDS) ----
        if (more) {
            const int wn = ww + 1;
            half8 th = *(const half8*)(&t1L[wn][ci * 8]);
            #pragma unroll
            for (int s2 = 0; s2 < 6; ++s2) {
                int k = s2 * 8 + k0;
                half8 wv = *(const half8*)(W1c + k * HID + ci * 8);
                *(half8*)(AsT[nxt] + k * HID + ((ci ^ (k & 7)) * 8)) = wv * th;
            }
            if (tid < 32) {
                half8 hv = *(const half8*)(&h1L[wn][tid * 8]);
                *(half8*)(AsT[nxt] + 48 * HID + tid * 8) = hv;
            } else if (tid < 64) {
                half8 cv = *(const half8*)(&cL[wn][(tid - 32) * 8]);
                *(half8*)(AsT[nxt] + 49 * HID + (((tid - 32) ^ 1) * 8)) = cv;
            }
        }

        // ---- reductions ----
        #pragma unroll
        for (int off = 32; off > 0; off >>= 1) {
            rt1 += __shfl_down(rt1, off, 64);
            rt2 += __shfl_down(rt2, off, 64);
        }
        #pragma unroll
        for (int kt = 0; kt < 3; ++kt) {
            gp[kt] += __shfl_xor(gp[kt], 16, 64);
            gp[kt] += __shfl_xor(gp[kt], 32, 64);
        }
        if (lane == 0) { wred[cur][wave][0] = rt1; wred[cur][wave][1] = rt2; }
        if (lane < 16) {
            #pragma unroll
            for (int kt = 0; kt < 3; ++kt) gw[cur][wave][kt * 16 + lane] = gp[kt];
        }

        __syncthreads();   // AsT[nxt] ready; gw/wred[cur] ready

        // ---- final combine for walker ww (wave ww&3; parity protects) ----
        if (wave == (ww & 3)) {
            float ggp = 0.f, potp = 0.f;
            if (lane < NXD) {
                float g = gw[cur][0][lane] + gw[cur][1][lane]
                        + gw[cur][2][lane] + gw[cur][3][lane];
                ggp = g * g;
                float xq = xs[ww][lane];
                potp = 0.5f * xq * xq;
            }
            #pragma unroll
            for (int off = 32; off > 0; off >>= 1) {
                ggp  += __shfl_down(ggp, off, 64);
                potp += __shfl_down(potp, off, 64);
            }
            if (lane == 0) {
                float T1 = wred[cur][0][0] + wred[cur][1][0] + wred[cur][2][0] + wred[cur][3][0];
                float T2 = wred[cur][0][1] + wred[cur][1][1] + wred[cur][2][1] + wred[cur][3][1];
                float kin = T1 + T2 - 0.5f * ggp;

                float x0 = xs[ww][0], x1 = xs[ww][1], x2 = xs[ww][2];
                float x3 = xs[ww][3], x4 = xs[ww][4], x5 = xs[ww][5];
                float d01 = (x0-x1)*(x0-x1) + (x2-x1)*(x2-x1);
                float d02 = (x0-x2)*(x0-x2) + (x1-x2)*(x1-x2);
                float d12 = (x3-x5)*(x3-x5) + (x4-x5)*(x4-x5);
                float inter = GCONST * (expf(-2.f*d01) + expf(-2.f*d02) + expf(-2.f*d12));

                out[wg]             = kin + potp + inter;
                out[NWALK + wg]     = kin;
                out[2 * NWALK + wg] = potp;
                out[3 * NWALK + wg] = inter;
            }
        }
    }
}

extern "C" void kernel_launch(void* const* d_in, const int* in_sizes, int n_in,
                              void* d_out, int out_size, void* d_ws, size_t ws_size,
                              hipStream_t stream) {
    const float* x  = (const float*)d_in[0];
    const float* W1 = (const float*)d_in[1];
    const float* b1 = (const float*)d_in[2];
    const float* W2 = (const float*)d_in[3];
    const float* b2 = (const float*)d_in[4];
    const float* w3 = (const float*)d_in[5];
    float* out = (float*)d_out;

    char* ws = (char*)d_ws;
    _Float16* W2c = (_Float16*)(ws);                       // 128 KB
    _Float16* W1c = (_Float16*)(ws + 131072);              // 24 KB

    prep_w<<<16, 256, 0, stream>>>(W2, W1, W2c, W1c);
    eloc8<<<NWALK / WPB, 256, 0, stream>>>(x, W1, b1, b2, w3, W2c, W1c, out);
}

// Round 13
// 136.211 us; speedup vs baseline: 1.4688x; 1.2906x over previous
//
#include <hip/hip_runtime.h>
#include <cmath>

#define NWALK 4096
#define NXD   48
#define HID   256
#define WPB   8
#define GCONST 0.7978845608028654f

typedef _Float16 half8   __attribute__((ext_vector_type(8)));
typedef float    float4v __attribute__((ext_vector_type(4)));

// ---------- prep_w: W2c[j*256+i] = fp16(W2[i*256+j]) (tiled transpose) + W1 fp16 cast
__global__ __launch_bounds__(256) void prep_w(const float* __restrict__ W2,
                                              const float* __restrict__ W1,
                                              _Float16* __restrict__ W2c,
                                              _Float16* __restrict__ W1c) {
    __shared__ float tile[64][65];
    const int bi = blockIdx.x & 3;
    const int bj = blockIdx.x >> 2;
    const int tx = threadIdx.x & 63;
    const int ty = threadIdx.x >> 6;
    #pragma unroll
    for (int r = 0; r < 16; ++r) {
        int il = ty * 16 + r;
        tile[tx][il] = W2[(bi * 64 + il) * HID + bj * 64 + tx];
    }
    __syncthreads();
    #pragma unroll
    for (int r = 0; r < 16; ++r) {
        int jl = ty * 16 + r;
        W2c[(bj * 64 + jl) * HID + bi * 64 + tx] = (_Float16)tile[jl][tx];
    }
    #pragma unroll
    for (int r = 0; r < 3; ++r) {
        int k = blockIdx.x * 3 + r;
        W1c[k * HID + threadIdx.x] = (_Float16)W1[k * HID + threadIdx.x];
    }
}

// ---------- eloc8: in-block layer-1 FIRST (low pressure), THEN A-residency + kt-split
__global__ __launch_bounds__(256, 2) void eloc8(
    const float* __restrict__ x,
    const float* __restrict__ W1,
    const float* __restrict__ b1,
    const float* __restrict__ b2,
    const float* __restrict__ w3,
    const _Float16* __restrict__ W2c,
    const _Float16* __restrict__ W1c,
    float* __restrict__ out)
{
    __shared__ __align__(16) _Float16 AsT[2][50 * HID];   // 51.2 KB, walker-parity
    __shared__ __align__(16) _Float16 t1L[WPB][HID];      // 4 KB
    __shared__ __align__(16) _Float16 h1L[WPB][HID];      // 4 KB
    __shared__ __align__(16) _Float16 cL[WPB][HID];       // 4 KB
    __shared__ float xs[WPB][NXD];
    __shared__ float b2s[HID], w3s[HID];
    __shared__ float a2s[HID], ps[HID], us[HID], uh2s[HID];
    __shared__ float gw[2][4][NXD];                       // parity-buffered
    __shared__ float wred[2][4][2];                       // parity-buffered

    const int w0   = blockIdx.x * WPB;
    const int tid  = threadIdx.x;
    const int wave = tid >> 6;
    const int lane = tid & 63;
    const int n16  = lane & 15;
    const int quad = (tid >> 4) & 3;
    const int ci   = tid & 31;     // staging i-chunk
    const int k0   = tid >> 5;     // staging k-row base

    // block-constant staging
    b2s[tid] = b2[tid];
    w3s[tid] = w3[tid];
    #pragma unroll
    for (int t = tid; t < WPB * NXD; t += 256)
        ((float*)xs)[t] = x[w0 * NXD + t];
    __syncthreads();   // xs ready

    // ---- in-block layer 1 FIRST (low register pressure): thread = hidden unit i ----
    {
        const int i = tid;
        const float b = b1[i];
        float a1[WPB];
        #pragma unroll
        for (int w = 0; w < WPB; ++w) a1[w] = b;
        float S = 0.f;
        #pragma unroll
        for (int k = 0; k < NXD; ++k) {
            float v = W1[k * HID + i];              // coalesced
            S = fmaf(v, v, S);
            #pragma unroll
            for (int w = 0; w < WPB; ++w)
                a1[w] = fmaf(xs[w][k], v, a1[w]);
        }
        #pragma unroll
        for (int w = 0; w < WPB; ++w) {
            float h1 = tanhf(a1[w]);
            float t1 = 1.f - h1 * h1;
            t1L[w][i] = (_Float16)t1;
            h1L[w][i] = (_Float16)h1;
            cL[w][i]  = (_Float16)(S * h1 * t1);
        }
    }
    __syncthreads();   // t1L/h1L/cL ready — scheduler region boundary

    // ---- NOW load A-fragments (128 regs); latency overlaps walker-0 staging ----
    half8 afr[8][4];
    #pragma unroll
    for (int s = 0; s < 8; ++s)
        #pragma unroll
        for (int a = 0; a < 4; ++a)
            afr[s][a] = *(const half8*)(W2c + ((wave * 4 + a) * 16 + n16) * HID
                                        + s * 32 + quad * 8);

    // stage walker 0 into buffer 0
    {
        half8 th = *(const half8*)(&t1L[0][ci * 8]);
        #pragma unroll
        for (int s2 = 0; s2 < 6; ++s2) {
            int k = s2 * 8 + k0;
            half8 wv = *(const half8*)(W1c + k * HID + ci * 8);
            *(half8*)(AsT[0] + k * HID + ((ci ^ (k & 7)) * 8)) = wv * th;
        }
        if (tid < 32) {
            half8 hv = *(const half8*)(&h1L[0][tid * 8]);
            *(half8*)(AsT[0] + 48 * HID + tid * 8) = hv;                  // 48&7=0
        } else if (tid < 64) {
            int c2 = tid - 32;
            half8 cv = *(const half8*)(&cL[0][c2 * 8]);
            *(half8*)(AsT[0] + 49 * HID + ((c2 ^ 1) * 8)) = cv;           // 49&7=1
        }
    }
    __syncthreads();

    for (int ww = 0; ww < WPB; ++ww) {
        const int cur = ww & 1, nxt = cur ^ 1;
        const int wg  = w0 + ww;
        const _Float16* curA = AsT[cur];
        const bool more = (ww + 1 < WPB);

        // ---- pass kt=3 first: a2 (col 0) / p (col 1) ----
        {
            float4v acc[4];
            #pragma unroll
            for (int a = 0; a < 4; ++a) acc[a] = (float4v){0.f, 0.f, 0.f, 0.f};
            const int krow = 48 + (n16 & 1);
            #pragma unroll
            for (int s = 0; s < 8; ++s) {
                half8 bf = *(const half8*)(curA + krow * HID
                            + ((((s * 4 + quad) ^ (krow & 7)) << 3)));
                #pragma unroll
                for (int a = 0; a < 4; ++a)
                    acc[a] = __builtin_amdgcn_mfma_f32_16x16x32_f16(
                        afr[s][a], bf, acc[a], 0, 0, 0);
            }
            if (n16 == 0) {
                #pragma unroll
                for (int a = 0; a < 4; ++a)
                    #pragma unroll
                    for (int reg = 0; reg < 4; ++reg)
                        a2s[(wave * 4 + a) * 16 + quad * 4 + reg] = acc[a][reg];
            } else if (n16 == 1) {
                #pragma unroll
                for (int a = 0; a < 4; ++a)
                    #pragma unroll
                    for (int reg = 0; reg < 4; ++reg)
                        ps[(wave * 4 + a) * 16 + quad * 4 + reg] = acc[a][reg];
            }
        }

        // ---- distributed activation: 1 tanh per thread (wave-local LDS) ----
        float a2v = a2s[tid] + b2s[tid];
        float h2  = tanhf(a2v);
        float t2  = 1.f - h2 * h2;
        float u   = w3s[tid] * t2;
        us[tid]   = u;
        uh2s[tid] = u * h2;
        float rt2 = u * ps[tid];

        // vectorized uu/uh preload (8 x ds_read_b128, 32 regs)
        float4v uu_r[4], uh_r[4];
        #pragma unroll
        for (int a = 0; a < 4; ++a) {
            int j0 = (wave * 4 + a) * 16 + quad * 4;
            uu_r[a] = *(const float4v*)(us + j0);
            uh_r[a] = *(const float4v*)(uh2s + j0);
        }

        // ---- kt = 0..2 passes, 16-reg accumulator reused, immediate fold ----
        float rt1 = 0.f;
        float gp[3];
        #pragma unroll 1
        for (int kt = 0; kt < 3; ++kt) {
            float4v acc[4];
            #pragma unroll
            for (int a = 0; a < 4; ++a) acc[a] = (float4v){0.f, 0.f, 0.f, 0.f};
            const int krow = kt * 16 + n16;
            #pragma unroll
            for (int s = 0; s < 8; ++s) {
                half8 bf = *(const half8*)(curA + krow * HID
                            + ((((s * 4 + quad) ^ (krow & 7)) << 3)));
                #pragma unroll
                for (int a = 0; a < 4; ++a)
                    acc[a] = __builtin_amdgcn_mfma_f32_16x16x32_f16(
                        afr[s][a], bf, acc[a], 0, 0, 0);
            }
            float g = 0.f;
            #pragma unroll
            for (int a = 0; a < 4; ++a)
                #pragma unroll
                for (int reg = 0; reg < 4; ++reg) {
                    float m = acc[a][reg];
                    rt1 = fmaf(m * m, uh_r[a][reg], rt1);
                    g   = fmaf(m, uu_r[a][reg], g);
                }
            gp[kt] = g;
        }

        // ---- stage next walker into other buffer (sources in LDS) ----
        if (more) {
            const int wn = ww + 1;
            half8 th = *(const half8*)(&t1L[wn][ci * 8]);
            #pragma unroll
            for (int s2 = 0; s2 < 6; ++s2) {
                int k = s2 * 8 + k0;
                half8 wv = *(const half8*)(W1c + k * HID + ci * 8);
                *(half8*)(AsT[nxt] + k * HID + ((ci ^ (k & 7)) * 8)) = wv * th;
            }
            if (tid < 32) {
                half8 hv = *(const half8*)(&h1L[wn][tid * 8]);
                *(half8*)(AsT[nxt] + 48 * HID + tid * 8) = hv;
            } else if (tid < 64) {
                half8 cv = *(const half8*)(&cL[wn][(tid - 32) * 8]);
                *(half8*)(AsT[nxt] + 49 * HID + (((tid - 32) ^ 1) * 8)) = cv;
            }
        }

        // ---- reductions ----
        #pragma unroll
        for (int off = 32; off > 0; off >>= 1) {
            rt1 += __shfl_down(rt1, off, 64);
            rt2 += __shfl_down(rt2, off, 64);
        }
        #pragma unroll
        for (int kt = 0; kt < 3; ++kt) {
            gp[kt] += __shfl_xor(gp[kt], 16, 64);
            gp[kt] += __shfl_xor(gp[kt], 32, 64);
        }
        if (lane == 0) { wred[cur][wave][0] = rt1; wred[cur][wave][1] = rt2; }
        if (lane < 16) {
            #pragma unroll
            for (int kt = 0; kt < 3; ++kt) gw[cur][wave][kt * 16 + lane] = gp[kt];
        }

        __syncthreads();   // AsT[nxt] ready; gw/wred[cur] ready

        // ---- final combine for walker ww (wave ww&3; parity protects) ----
        if (wave == (ww & 3)) {
            float ggp = 0.f, potp = 0.f;
            if (lane < NXD) {
                float g = gw[cur][0][lane] + gw[cur][1][lane]
                        + gw[cur][2][lane] + gw[cur][3][lane];
                ggp = g * g;
                float xq = xs[ww][lane];
                potp = 0.5f * xq * xq;
            }
            #pragma unroll
            for (int off = 32; off > 0; off >>= 1) {
                ggp  += __shfl_down(ggp, off, 64);
                potp += __shfl_down(potp, off, 64);
            }
            if (lane == 0) {
                float T1 = wred[cur][0][0] + wred[cur][1][0] + wred[cur][2][0] + wred[cur][3][0];
                float T2 = wred[cur][0][1] + wred[cur][1][1] + wred[cur][2][1] + wred[cur][3][1];
                float kin = T1 + T2 - 0.5f * ggp;

                float x0 = xs[ww][0], x1 = xs[ww][1], x2 = xs[ww][2];
                float x3 = xs[ww][3], x4 = xs[ww][4], x5 = xs[ww][5];
                float d01 = (x0-x1)*(x0-x1) + (x2-x1)*(x2-x1);
                float d02 = (x0-x2)*(x0-x2) + (x1-x2)*(x1-x2);
                float d12 = (x3-x5)*(x3-x5) + (x4-x5)*(x4-x5);
                float inter = GCONST * (expf(-2.f*d01) + expf(-2.f*d02) + expf(-2.f*d12));

                out[wg]             = kin + potp + inter;
                out[NWALK + wg]     = kin;
                out[2 * NWALK + wg] = potp;
                out[3 * NWALK + wg] = inter;
            }
        }
    }
}

extern "C" void kernel_launch(void* const* d_in, const int* in_sizes, int n_in,
                              void* d_out, int out_size, void* d_ws, size_t ws_size,
                              hipStream_t stream) {
    const float* x  = (const float*)d_in[0];
    const float* W1 = (const float*)d_in[1];
    const float* b1 = (const float*)d_in[2];
    const float* W2 = (const float*)d_in[3];
    const float* b2 = (const float*)d_in[4];
    const float* w3 = (const float*)d_in[5];
    float* out = (float*)d_out;

    char* ws = (char*)d_ws;
    _Float16* W2c = (_Float16*)(ws);                       // 128 KB
    _Float16* W1c = (_Float16*)(ws + 131072);              // 24 KB

    prep_w<<<16, 256, 0, stream>>>(W2, W1, W2c, W1c);
    eloc8<<<NWALK / WPB, 256, 0, stream>>>(x, W1, b1, b2, w3, W2c, W1c, out);
}

// Round 14
// 136.093 us; speedup vs baseline: 1.4701x; 1.0009x over previous
//
#include <hip/hip_runtime.h>
#include <cmath>

#define NWALK 4096
#define NXD   48
#define HID   256
#define WPB   8
#define GCONST 0.7978845608028654f

typedef _Float16 half8   __attribute__((ext_vector_type(8)));
typedef float    float4v __attribute__((ext_vector_type(4)));

// ---------- prep_w: W2c[j*256+i] = fp16(W2[i*256+j]) (tiled transpose) + W1 fp16 cast
__global__ __launch_bounds__(256) void prep_w(const float* __restrict__ W2,
                                              const float* __restrict__ W1,
                                              _Float16* __restrict__ W2c,
                                              _Float16* __restrict__ W1c) {
    __shared__ float tile[64][65];
    const int bi = blockIdx.x & 3;
    const int bj = blockIdx.x >> 2;
    const int tx = threadIdx.x & 63;
    const int ty = threadIdx.x >> 6;
    #pragma unroll
    for (int r = 0; r < 16; ++r) {
        int il = ty * 16 + r;
        tile[tx][il] = W2[(bi * 64 + il) * HID + bj * 64 + tx];
    }
    __syncthreads();
    #pragma unroll
    for (int r = 0; r < 16; ++r) {
        int jl = ty * 16 + r;
        W2c[(bj * 64 + jl) * HID + bi * 64 + tx] = (_Float16)tile[jl][tx];
    }
    #pragma unroll
    for (int r = 0; r < 3; ++r) {
        int k = blockIdx.x * 3 + r;
        W1c[k * HID + threadIdx.x] = (_Float16)W1[k * HID + threadIdx.x];
    }
}

// ---------- eloc8: in-block layer-1 first; afr loads FORCED after via LDS data dep
__global__ __launch_bounds__(256, 2) void eloc8(
    const float* __restrict__ x,
    const float* __restrict__ W1,
    const float* __restrict__ b1,
    const float* __restrict__ b2,
    const float* __restrict__ w3,
    const _Float16* __restrict__ W2c,
    const _Float16* __restrict__ W1c,
    float* __restrict__ out)
{
    __shared__ __align__(16) _Float16 AsT[2][50 * HID];   // 51.2 KB, walker-parity
    __shared__ __align__(16) _Float16 t1L[WPB][HID];      // 4 KB
    __shared__ __align__(16) _Float16 h1L[WPB][HID];      // 4 KB
    __shared__ __align__(16) _Float16 cL[WPB][HID];       // 4 KB
    __shared__ float xs[WPB][NXD];
    __shared__ float b2s[HID], w3s[HID];
    __shared__ float a2s[HID], ps[HID], us[HID], uh2s[HID];
    __shared__ float gw[2][4][NXD];                       // parity-buffered
    __shared__ float wred[2][4][2];                       // parity-buffered
    __shared__ int zeroL;                                 // anti-hoist anchor

    const int w0   = blockIdx.x * WPB;
    const int tid  = threadIdx.x;
    const int wave = tid >> 6;
    const int lane = tid & 63;
    const int n16  = lane & 15;
    const int quad = (tid >> 4) & 3;
    const int ci   = tid & 31;     // staging i-chunk
    const int k0   = tid >> 5;     // staging k-row base

    // block-constant staging
    b2s[tid] = b2[tid];
    w3s[tid] = w3[tid];
    if (tid == 0) zeroL = (w0 >> 20);   // always 0, opaque to compiler
    #pragma unroll
    for (int t = tid; t < WPB * NXD; t += 256)
        ((float*)xs)[t] = x[w0 * NXD + t];
    __syncthreads();   // xs ready

    // ---- in-block layer 1 FIRST (low register pressure): thread = hidden unit i ----
    {
        const int i = tid;
        const float b = b1[i];
        float a1[WPB];
        #pragma unroll
        for (int w = 0; w < WPB; ++w) a1[w] = b;
        float S = 0.f;
        #pragma unroll
        for (int k = 0; k < NXD; ++k) {
            float v = W1[k * HID + i];              // coalesced
            S = fmaf(v, v, S);
            #pragma unroll
            for (int w = 0; w < WPB; ++w)
                a1[w] = fmaf(xs[w][k], v, a1[w]);
        }
        #pragma unroll
        for (int w = 0; w < WPB; ++w) {
            float h1 = tanhf(a1[w]);
            float t1 = 1.f - h1 * h1;
            t1L[w][i] = (_Float16)t1;
            h1L[w][i] = (_Float16)h1;
            cL[w][i]  = (_Float16)(S * h1 * t1);
        }
    }
    __syncthreads();   // t1L/h1L/cL ready

    // ---- afr loads AFTER layer-1, pinned by LDS data dependency (dz == 0) ----
    const int dz = zeroL;                       // ds_read after barrier; cannot hoist
    const _Float16* W2cd = W2c + dz;            // global loads depend on dz
    half8 afr[8][4];
    #pragma unroll
    for (int s = 0; s < 8; ++s)
        #pragma unroll
        for (int a = 0; a < 4; ++a)
            afr[s][a] = *(const half8*)(W2cd + ((wave * 4 + a) * 16 + n16) * HID
                                        + s * 32 + quad * 8);

    // stage walker 0 into buffer 0 (overlaps afr L2 latency)
    {
        half8 th = *(const half8*)(&t1L[0][ci * 8]);
        #pragma unroll
        for (int s2 = 0; s2 < 6; ++s2) {
            int k = s2 * 8 + k0;
            half8 wv = *(const half8*)(W1c + k * HID + ci * 8);
            *(half8*)(AsT[0] + k * HID + ((ci ^ (k & 7)) * 8)) = wv * th;
        }
        if (tid < 32) {
            half8 hv = *(const half8*)(&h1L[0][tid * 8]);
            *(half8*)(AsT[0] + 48 * HID + tid * 8) = hv;                  // 48&7=0
        } else if (tid < 64) {
            int c2 = tid - 32;
            half8 cv = *(const half8*)(&cL[0][c2 * 8]);
            *(half8*)(AsT[0] + 49 * HID + ((c2 ^ 1) * 8)) = cv;           // 49&7=1
        }
    }
    __syncthreads();

    for (int ww = 0; ww < WPB; ++ww) {
        const int cur = ww & 1, nxt = cur ^ 1;
        const int wg  = w0 + ww;
        const _Float16* curA = AsT[cur];
        const bool more = (ww + 1 < WPB);

        // ---- pass kt=3 first: a2 (col 0) / p (col 1) ----
        {
            float4v acc[4];
            #pragma unroll
            for (int a = 0; a < 4; ++a) acc[a] = (float4v){0.f, 0.f, 0.f, 0.f};
            const int krow = 48 + (n16 & 1);
            #pragma unroll
            for (int s = 0; s < 8; ++s) {
                half8 bf = *(const half8*)(curA + krow * HID
                            + ((((s * 4 + quad) ^ (krow & 7)) << 3)));
                #pragma unroll
                for (int a = 0; a < 4; ++a)
                    acc[a] = __builtin_amdgcn_mfma_f32_16x16x32_f16(
                        afr[s][a], bf, acc[a], 0, 0, 0);
            }
            if (n16 == 0) {
                #pragma unroll
                for (int a = 0; a < 4; ++a)
                    #pragma unroll
                    for (int reg = 0; reg < 4; ++reg)
                        a2s[(wave * 4 + a) * 16 + quad * 4 + reg] = acc[a][reg];
            } else if (n16 == 1) {
                #pragma unroll
                for (int a = 0; a < 4; ++a)
                    #pragma unroll
                    for (int reg = 0; reg < 4; ++reg)
                        ps[(wave * 4 + a) * 16 + quad * 4 + reg] = acc[a][reg];
            }
        }

        // ---- distributed activation: 1 tanh per thread (wave-local LDS) ----
        float a2v = a2s[tid] + b2s[tid];
        float h2  = tanhf(a2v);
        float t2  = 1.f - h2 * h2;
        float u   = w3s[tid] * t2;
        us[tid]   = u;
        uh2s[tid] = u * h2;
        float rt2 = u * ps[tid];

        // vectorized uu/uh preload (8 x ds_read_b128, 32 regs)
        float4v uu_r[4], uh_r[4];
        #pragma unroll
        for (int a = 0; a < 4; ++a) {
            int j0 = (wave * 4 + a) * 16 + quad * 4;
            uu_r[a] = *(const float4v*)(us + j0);
            uh_r[a] = *(const float4v*)(uh2s + j0);
        }

        // ---- kt = 0..2 passes, 16-reg accumulator reused, immediate fold ----
        float rt1 = 0.f;
        float gp[3];
        #pragma unroll 1
        for (int kt = 0; kt < 3; ++kt) {
            float4v acc[4];
            #pragma unroll
            for (int a = 0; a < 4; ++a) acc[a] = (float4v){0.f, 0.f, 0.f, 0.f};
            const int krow = kt * 16 + n16;
            #pragma unroll
            for (int s = 0; s < 8; ++s) {
                half8 bf = *(const half8*)(curA + krow * HID
                            + ((((s * 4 + quad) ^ (krow & 7)) << 3)));
                #pragma unroll
                for (int a = 0; a < 4; ++a)
                    acc[a] = __builtin_amdgcn_mfma_f32_16x16x32_f16(
                        afr[s][a], bf, acc[a], 0, 0, 0);
            }
            float g = 0.f;
            #pragma unroll
            for (int a = 0; a < 4; ++a)
                #pragma unroll
                for (int reg = 0; reg < 4; ++reg) {
                    float m = acc[a][reg];
                    rt1 = fmaf(m * m, uh_r[a][reg], rt1);
                    g   = fmaf(m, uu_r[a][reg], g);
                }
            gp[kt] = g;
        }

        // ---- stage next walker into other buffer (sources in LDS) ----
        if (more) {
            const int wn = ww + 1;
            half8 th = *(const half8*)(&t1L[wn][ci * 8]);
            #pragma unroll
            for (int s2 = 0; s2 < 6; ++s2) {
                int k = s2 * 8 + k0;
                half8 wv = *(const half8*)(W1c + k * HID + ci * 8);
                *(half8*)(AsT[nxt] + k * HID + ((ci ^ (k & 7)) * 8)) = wv * th;
            }
            if (tid < 32) {
                half8 hv = *(const half8*)(&h1L[wn][tid * 8]);
                *(half8*)(AsT[nxt] + 48 * HID + tid * 8) = hv;
            } else if (tid < 64) {
                half8 cv = *(const half8*)(&cL[wn][(tid - 32) * 8]);
                *(half8*)(AsT[nxt] + 49 * HID + (((tid - 32) ^ 1) * 8)) = cv;
            }
        }

        // ---- reductions ----
        #pragma unroll
        for (int off = 32; off > 0; off >>= 1) {
            rt1 += __shfl_down(rt1, off, 64);
            rt2 += __shfl_down(rt2, off, 64);
        }
        #pragma unroll
        for (int kt = 0; kt < 3; ++kt) {
            gp[kt] += __shfl_xor(gp[kt], 16, 64);
            gp[kt] += __shfl_xor(gp[kt], 32, 64);
        }
        if (lane == 0) { wred[cur][wave][0] = rt1; wred[cur][wave][1] = rt2; }
        if (lane < 16) {
            #pragma unroll
            for (int kt = 0; kt < 3; ++kt) gw[cur][wave][kt * 16 + lane] = gp[kt];
        }

        __syncthreads();   // AsT[nxt] ready; gw/wred[cur] ready

        // ---- final combine for walker ww (wave ww&3; parity protects) ----
        if (wave == (ww & 3)) {
            float ggp = 0.f, potp = 0.f;
            if (lane < NXD) {
                float g = gw[cur][0][lane] + gw[cur][1][lane]
                        + gw[cur][2][lane] + gw[cur][3][lane];
                ggp = g * g;
                float xq = xs[ww][lane];
                potp = 0.5f * xq * xq;
            }
            #pragma unroll
            for (int off = 32; off > 0; off >>= 1) {
                ggp  += __shfl_down(ggp, off, 64);
                potp += __shfl_down(potp, off, 64);
            }
            if (lane == 0) {
                float T1 = wred[cur][0][0] + wred[cur][1][0] + wred[cur][2][0] + wred[cur][3][0];
                float T2 = wred[cur][0][1] + wred[cur][1][1] + wred[cur][2][1] + wred[cur][3][1];
                float kin = T1 + T2 - 0.5f * ggp;

                float x0 = xs[ww][0], x1 = xs[ww][1], x2 = xs[ww][2];
                float x3 = xs[ww][3], x4 = xs[ww][4], x5 = xs[ww][5];
                float d01 = (x0-x1)*(x0-x1) + (x2-x1)*(x2-x1);
                float d02 = (x0-x2)*(x0-x2) + (x1-x2)*(x1-x2);
                float d12 = (x3-x5)*(x3-x5) + (x4-x5)*(x4-x5);
                float inter = GCONST * (expf(-2.f*d01) + expf(-2.f*d02) + expf(-2.f*d12));

                out[wg]             = kin + potp + inter;
                out[NWALK + wg]     = kin;
                out[2 * NWALK + wg] = potp;
                out[3 * NWALK + wg] = inter;
            }
        }
    }
}

extern "C" void kernel_launch(void* const* d_in, const int* in_sizes, int n_in,
                              void* d_out, int out_size, void* d_ws, size_t ws_size,
                              hipStream_t stream) {
    const float* x  = (const float*)d_in[0];
    const float* W1 = (const float*)d_in[1];
    const float* b1 = (const float*)d_in[2];
    const float* W2 = (const float*)d_in[3];
    const float* b2 = (const float*)d_in[4];
    const float* w3 = (const float*)d_in[5];
    float* out = (float*)d_out;

    char* ws = (char*)d_ws;
    _Float16* W2c = (_Float16*)(ws);                       // 128 KB
    _Float16* W1c = (_Float16*)(ws + 131072);              // 24 KB

    prep_w<<<16, 256, 0, stream>>>(W2, W1, W2c, W1c);
    eloc8<<<NWALK / WPB, 256, 0, stream>>>(x, W1, b1, b2, w3, W2c, W1c, out);
}